// Round 1
// 495.419 us; speedup vs baseline: 1.2122x; 1.2122x over previous
//
#include <hip/hip_runtime.h>
#include <hip/hip_bf16.h>
#include <cstdint>

typedef __attribute__((ext_vector_type(8))) short short8;
typedef __attribute__((ext_vector_type(4))) float floatx4;
typedef __hip_bfloat16 bf16;
typedef unsigned short u16;

static constexpr int cN0 = 120000, cN1 = 24000, cN2 = 6000;
static constexpr int cD = 256, cHC1 = 512;
static constexpr int CH1 = 4800;   // layer-1 fallback chunk (5 chunks, %64==0)

__device__ __forceinline__ float dot4(float4 a, float4 b) {
  return a.x * b.x + a.y * b.y + a.z * b.z + a.w * b.w;
}

// ---------- W1t[n*256+k] = bf16(W1[k*512+n]) ----------
__global__ __launch_bounds__(256)
void gat_w1t(const float* __restrict__ W1, u16* __restrict__ dst) {
  int t = blockIdx.x * 256 + threadIdx.x;  // t = n*256+k
  if (t >= 512 * 256) return;
  int n = t >> 8, k = t & 255;
  bf16 v = bf16(W1[(size_t)k * 512 + n]);
  dst[t] = *(u16*)&v;
}

// ---------- W2te[c*4096 + h*512 + k] = bf16(W2[k*2048 + h*256 + c]) ----------
__global__ __launch_bounds__(256)
void gat_make_w2te(const float* __restrict__ W2, u16* __restrict__ out) {
  __shared__ u16 tile[32][33];
  int kt = blockIdx.x * 32, ct = blockIdx.y * 32, h = blockIdx.z;
  int tx = threadIdx.x & 31, ty4 = (threadIdx.x >> 5) * 4;
#pragma unroll
  for (int i = 0; i < 4; i++) {
    int k = kt + ty4 + i, c = ct + tx;
    bf16 v = bf16(W2[(size_t)k * 2048 + h * 256 + c]);
    tile[ty4 + i][tx] = *(u16*)&v;
  }
  __syncthreads();
#pragma unroll
  for (int i = 0; i < 4; i++) {
    int c = ct + ty4 + i, k = kt + tx;
    out[(size_t)c * 4096 + h * 512 + k] = tile[tx][ty4 + i];
  }
}

// ---------- watt[h*K+k] = sum_c W[k*ldw + h*Ch + c] * att[h*Ch+c]  (f32) ----------
__global__ __launch_bounds__(256)
void gat_make_watt(const float* __restrict__ W, const float* __restrict__ atts,
                   const float* __restrict__ attd, float* __restrict__ ws,
                   float* __restrict__ wd, int K, int Ch, int ldw) {
  int lane = threadIdx.x & 63;
  int task = blockIdx.x * 4 + (threadIdx.x >> 6);  // task = h*K + k
  if (task >= 8 * K) return;
  int h = task / K, k = task - h * K;
  const float* Wr = W + (size_t)k * ldw + h * Ch;
  const float* as = atts + h * Ch;
  const float* ad = attd + h * Ch;
  float ss = 0.f, dd = 0.f;
  for (int c = lane; c < Ch; c += 64) {
    float wv = Wr[c];
    ss += wv * as[c];
    dd += wv * ad[c];
  }
#pragma unroll
  for (int o = 32; o; o >>= 1) { ss += __shfl_down(ss, o); dd += __shfl_down(dd, o); }
  if (lane == 0) { ws[task] = ss; wd[task] = dd; }
}

// ---- transposed butterfly reduce: 16 partials over 64 lanes in 15 shfl ----
#define RSTAGE(HALF, MASK)                                              \
  {                                                                     \
    _Pragma("unroll") for (int j = 0; j < HALF; j++) {                  \
      float send = (lane & MASK) ? v[j] : v[j + HALF];                  \
      float rcv = __shfl_xor(send, MASK);                               \
      v[j] = ((lane & MASK) ? v[j + HALF] : v[j]) + rcv;                \
    }                                                                   \
  }

// ---------- scores K=256: one row per wave, w in 64 VGPRs ----------
__global__ __launch_bounds__(256)
void gat_scores_reg(const float* __restrict__ x, const float* __restrict__ wsrc,
                    const float* __restrict__ wdst, float* __restrict__ a_s,
                    float* __restrict__ a_d, int M, int MD) {
  int lane = threadIdx.x & 63;
  int wv = (blockIdx.x * 256 + threadIdx.x) >> 6;
  int nw = (gridDim.x * 256) >> 6;
  float4 w[16];
#pragma unroll
  for (int j = 0; j < 8; j++) {
    w[j]     = *(const float4*)&wsrc[j * 256 + lane * 4];
    w[j + 8] = *(const float4*)&wdst[j * 256 + lane * 4];
  }
  for (int row = wv; row < M; row += nw) {
    float4 xv = *(const float4*)&x[(size_t)row * 256 + lane * 4];
    float v[16];
#pragma unroll
    for (int j = 0; j < 16; j++) v[j] = dot4(xv, w[j]);
    RSTAGE(8, 1) RSTAGE(4, 2) RSTAGE(2, 4) RSTAGE(1, 8)
    v[0] += __shfl_xor(v[0], 16);
    v[0] += __shfl_xor(v[0], 32);
    if (lane < 16) {
      int o = ((lane & 1) << 3) | ((lane & 2) << 1) | ((lane & 4) >> 1) | ((lane & 8) >> 3);
      if (o < 8) a_s[row * 8 + o] = v[0];
      else if (row < MD) a_d[row * 8 + (o - 8)] = v[0];
    }
  }
}

// ---------- scores K=512: w staged in LDS (32 KB), one row per wave ----------
__global__ __launch_bounds__(256)
void gat_scores_w512(const float* __restrict__ x, const float* __restrict__ wsrc,
                     const float* __restrict__ wdst, float* __restrict__ a_s,
                     float* __restrict__ a_d, int M, int MD) {
  __shared__ float wl[16 * 512];
  int tid = threadIdx.x;
#pragma unroll
  for (int base = 0; base < 8192; base += 1024) {
    int idx = base + tid * 4;
    int j = idx >> 9, c = idx & 511;
    *(float4*)&wl[idx] = (j < 8) ? *(const float4*)&wsrc[j * 512 + c]
                                 : *(const float4*)&wdst[(j - 8) * 512 + c];
  }
  __syncthreads();
  int lane = tid & 63;
  int wv = (blockIdx.x * 256 + tid) >> 6;
  int nw = (gridDim.x * 256) >> 6;
  for (int row = wv; row < M; row += nw) {
    float4 xa = *(const float4*)&x[(size_t)row * 512 + lane * 4];
    float4 xb = *(const float4*)&x[(size_t)row * 512 + 256 + lane * 4];
    float v[16];
#pragma unroll
    for (int j = 0; j < 16; j++) {
      float4 wa = *(const float4*)&wl[j * 512 + lane * 4];
      float4 wb = *(const float4*)&wl[j * 512 + 256 + lane * 4];
      v[j] = dot4(xa, wa) + dot4(xb, wb);
    }
    RSTAGE(8, 1) RSTAGE(4, 2) RSTAGE(2, 4) RSTAGE(1, 8)
    v[0] += __shfl_xor(v[0], 16);
    v[0] += __shfl_xor(v[0], 32);
    if (lane < 16) {
      int o = ((lane & 1) << 3) | ((lane & 2) << 1) | ((lane & 4) >> 1) | ((lane & 8) >> 3);
      if (o < 8) a_s[row * 8 + o] = v[0];
      else if (row < MD) a_d[row * 8 + (o - 8)] = v[0];
    }
  }
}

// ---------- CSR build ----------
__global__ __launch_bounds__(256)
void gat_hist(const int* __restrict__ dstv, int* __restrict__ cnt, int E) {
  int t = blockIdx.x * 256 + threadIdx.x;
  if (t < E) atomicAdd(&cnt[dstv[t]], 1);
}

// 3-kernel parallel exclusive scan (replaces single-CU serial scan)
__global__ __launch_bounds__(1024)
void gat_scan1(const int* __restrict__ cnt, int* __restrict__ off,
               int* __restrict__ bsum, int n) {
  __shared__ int wsum[16];
  int t = threadIdx.x, lane = t & 63, wid = t >> 6;
  int idx = blockIdx.x * 1024 + t;
  int v = (idx < n) ? cnt[idx] : 0;
  int x = v;
#pragma unroll
  for (int d = 1; d < 64; d <<= 1) { int y = __shfl_up(x, d); if (lane >= d) x += y; }
  if (lane == 63) wsum[wid] = x;
  __syncthreads();
  if (t < 16) {
    int s = wsum[t];
#pragma unroll
    for (int d = 1; d < 16; d <<= 1) { int y = __shfl_up(s, d); if (t >= d) s += y; }
    wsum[t] = s;
  }
  __syncthreads();
  int excl = (wid ? wsum[wid - 1] : 0) + x - v;
  if (idx < n) off[idx] = excl;
  if (t == 1023) bsum[blockIdx.x] = wsum[15];
}

__global__ __launch_bounds__(64)
void gat_scan2(int* __restrict__ bsum, int nb, int* __restrict__ off, int n) {
  int t = threadIdx.x;
  int v = (t < nb) ? bsum[t] : 0;
  int x = v;
#pragma unroll
  for (int d = 1; d < 64; d <<= 1) { int y = __shfl_up(x, d); if (t >= d) x += y; }
  if (t < nb) bsum[t] = x - v;   // exclusive block offsets
  if (t == 63) off[n] = x;       // grand total
}

__global__ __launch_bounds__(256)
void gat_scan3(int* __restrict__ off, const int* __restrict__ bsum, int n) {
  int i = blockIdx.x * 256 + threadIdx.x;
  if (i < n) off[i] += bsum[i >> 10];
}

// ---------- fused scatter+edge ----------
__global__ __launch_bounds__(256)
void gat_scatter_edge(const int* __restrict__ src, const int* __restrict__ dstv,
                      const float* __restrict__ a_s, const float* __restrict__ a_d,
                      const int* __restrict__ off, int* __restrict__ cur,
                      int* __restrict__ srcs, float* __restrict__ exs, int E) {
  int t = blockIdx.x * 256 + threadIdx.x;
  if (t >= E) return;
  int s = src[t], d = dstv[t];
  int slot = off[d] + atomicAdd(&cur[d], 1);
  srcs[slot] = s;
  const float* as = a_s + (size_t)s * 8;
  const float* ad = a_d + (size_t)d * 8;
  float4 s0 = *(const float4*)as, s1 = *(const float4*)(as + 4);
  float4 d0 = *(const float4*)ad, d1 = *(const float4*)(ad + 4);
  float ev[8] = { s0.x + d0.x, s0.y + d0.y, s0.z + d0.z, s0.w + d0.w,
                  s1.x + d1.x, s1.y + d1.y, s1.z + d1.z, s1.w + d1.w };
  float exv[8];
#pragma unroll
  for (int h = 0; h < 8; h++) {
    float e = ev[h];
    e = e > 0.f ? e : 0.2f * e;
    exv[h] = expf(e);  // shift-invariant softmax; |e| <~ 8 so no overflow
  }
  float4* op = (float4*)(exs + (size_t)slot * 8);
  op[0] = make_float4(exv[0], exv[1], exv[2], exv[3]);
  op[1] = make_float4(exv[4], exv[5], exv[6], exv[7]);
}

// ---------- layer-1 input-space gather, fused denominator, 2-edge unroll ----------
__global__ __launch_bounds__(256)
void gat_gather_in1(const float* __restrict__ x, const float* __restrict__ exs,
                    const int* __restrict__ off, const int* __restrict__ srcs,
                    u16* __restrict__ agg, int d0) {
  int d = d0 + blockIdx.x, t = threadIdx.x;  // t = k (0..255)
  int beg = off[d], end = off[d + 1];
  float acc[8] = {}, den[8] = {};
  int i = beg;
  if ((end - beg) & 1) {
    int s = srcs[i];
    float ea[8];
    *(float4*)&ea[0] = *(const float4*)&exs[(size_t)i * 8];
    *(float4*)&ea[4] = *(const float4*)&exs[(size_t)i * 8 + 4];
    float xv = x[(size_t)s * cD + t];
#pragma unroll
    for (int j = 0; j < 8; j++) { acc[j] += ea[j] * xv; den[j] += ea[j]; }
    i++;
  }
  for (; i < end; i += 2) {
    int s0 = srcs[i], s1 = srcs[i + 1];
    float ea[8], eb[8];
    *(float4*)&ea[0] = *(const float4*)&exs[(size_t)i * 8];
    *(float4*)&ea[4] = *(const float4*)&exs[(size_t)i * 8 + 4];
    *(float4*)&eb[0] = *(const float4*)&exs[(size_t)(i + 1) * 8];
    *(float4*)&eb[4] = *(const float4*)&exs[(size_t)(i + 1) * 8 + 4];
    float xv0 = x[(size_t)s0 * cD + t];
    float xv1 = x[(size_t)s1 * cD + t];
#pragma unroll
    for (int j = 0; j < 8; j++) {
      acc[j] += ea[j] * xv0 + eb[j] * xv1;
      den[j] += ea[j] + eb[j];
    }
  }
  u16* ap = agg + (size_t)blockIdx.x * 2048 + t;
#pragma unroll
  for (int j = 0; j < 8; j++) {
    float inv = den[j] > 0.f ? 1.f / den[j] : 0.f;  // zero-degree -> 0 (matches ref)
    bf16 v = bf16(acc[j] * inv);
    ap[(size_t)j * 256] = *(u16*)&v;
  }
}

// ---------- layer-2 input-space gather, fused denominator, 2-edge unroll ----------
__global__ __launch_bounds__(256)
void gat_gather_in2(const float* __restrict__ x1, const float* __restrict__ exs,
                    const int* __restrict__ off, const int* __restrict__ srcs,
                    u16* __restrict__ agg, int d0) {
  int d = d0 + blockIdx.x, t = threadIdx.x;  // k pair: t, t+256
  int beg = off[d], end = off[d + 1];
  float acc0[8] = {}, acc1[8] = {}, den[8] = {};
  int i = beg;
  if ((end - beg) & 1) {
    int s = srcs[i];
    float ea[8];
    *(float4*)&ea[0] = *(const float4*)&exs[(size_t)i * 8];
    *(float4*)&ea[4] = *(const float4*)&exs[(size_t)i * 8 + 4];
    float xa = x1[(size_t)s * cHC1 + t];
    float xb = x1[(size_t)s * cHC1 + t + 256];
#pragma unroll
    for (int j = 0; j < 8; j++) { acc0[j] += ea[j] * xa; acc1[j] += ea[j] * xb; den[j] += ea[j]; }
    i++;
  }
  for (; i < end; i += 2) {
    int s0 = srcs[i], s1 = srcs[i + 1];
    float ea[8], eb[8];
    *(float4*)&ea[0] = *(const float4*)&exs[(size_t)i * 8];
    *(float4*)&ea[4] = *(const float4*)&exs[(size_t)i * 8 + 4];
    *(float4*)&eb[0] = *(const float4*)&exs[(size_t)(i + 1) * 8];
    *(float4*)&eb[4] = *(const float4*)&exs[(size_t)(i + 1) * 8 + 4];
    float xa0 = x1[(size_t)s0 * cHC1 + t];
    float xb0 = x1[(size_t)s0 * cHC1 + t + 256];
    float xa1 = x1[(size_t)s1 * cHC1 + t];
    float xb1 = x1[(size_t)s1 * cHC1 + t + 256];
#pragma unroll
    for (int j = 0; j < 8; j++) {
      acc0[j] += ea[j] * xa0 + eb[j] * xa1;
      acc1[j] += ea[j] * xb0 + eb[j] * xb1;
      den[j] += ea[j] + eb[j];
    }
  }
  u16* ap = agg + (size_t)blockIdx.x * 4096;
#pragma unroll
  for (int j = 0; j < 8; j++) {
    float inv = den[j] > 0.f ? 1.f / den[j] : 0.f;
    bf16 v0 = bf16(acc0[j] * inv), v1 = bf16(acc1[j] * inv);
    ap[(size_t)j * 512 + t]       = *(u16*)&v0;
    ap[(size_t)j * 512 + t + 256] = *(u16*)&v1;
  }
}

// ---------- GEMM: C = A[M,K] @ Bt[N,K]^T (bf16 in, f32 out), M-guarded ----------
// XOR-swizzled LDS: conflict-free b128. EPI=0: raw partial; EPI=1: elu(v+bias)
template<int BN, int EPI>
__global__ __launch_bounds__(256)
void gat_gemm(const u16* __restrict__ A, long lda, const u16* __restrict__ Bt, long ldb,
              float* __restrict__ C, long ldc, int M, int K,
              const float* __restrict__ bias, int zA, int zB, long zC, int zBias) {
  __shared__ __align__(16) u16 Al[64 * 64];
  __shared__ __align__(16) u16 Bl[BN * 64];
  const int tid = threadIdx.x;
  const int bm = blockIdx.x << 6;
  const int n0 = blockIdx.y * BN;
  const int z = blockIdx.z;
  const u16* Ab = A + (size_t)z * zA;
  const u16* Bb = Bt + (size_t)z * zB + (size_t)n0 * ldb;
  const int wid = tid >> 6, lane = tid & 63;
  const int wm = (wid & 1) << 5, wn = (wid >> 1) * (BN / 2);
  const int q = lane >> 4, r = lane & 15;
  constexpr int NJ = BN / 32;
  floatx4 acc[2][NJ] = {};
  const int arow = tid >> 3;      // 0..31
  const int chunk = tid & 7;      // 8-u16 chunk index
  const int acol = chunk << 3;
  for (int k0 = 0; k0 < K; k0 += 64) {
    __syncthreads();
#pragma unroll
    for (int rr = 0; rr < 2; rr++) {
      int row = arow + rr * 32;
      int gr = bm + row; if (gr >= M) gr = M - 1;
      *(uint4*)&Al[row * 64 + ((chunk ^ (row & 7)) << 3)] =
          *(const uint4*)&Ab[(size_t)gr * lda + k0 + acol];
    }
#pragma unroll
    for (int rr = 0; rr < BN / 32; rr++) {
      int row = arow + rr * 32;
      *(uint4*)&Bl[row * 64 + ((chunk ^ (row & 7)) << 3)] =
          *(const uint4*)&Bb[(size_t)row * ldb + k0 + acol];
    }
    __syncthreads();
#pragma unroll
    for (int kk = 0; kk < 64; kk += 32) {
      const int cs = (((kk >> 3) + q) ^ (r & 7)) << 3;
      short8 af[2], bfr[NJ];
#pragma unroll
      for (int i = 0; i < 2; i++)  af[i]  = *(const short8*)&Al[(wm + i * 16 + r) * 64 + cs];
#pragma unroll
      for (int j = 0; j < NJ; j++) bfr[j] = *(const short8*)&Bl[(wn + j * 16 + r) * 64 + cs];
#pragma unroll
      for (int i = 0; i < 2; i++)
#pragma unroll
        for (int j = 0; j < NJ; j++)
          acc[i][j] = __builtin_amdgcn_mfma_f32_16x16x32_bf16(af[i], bfr[j], acc[i][j], 0, 0, 0);
    }
  }
  // C/D layout: col = lane&15 (n), row = quad*4 + reg (m)
#pragma unroll
  for (int i = 0; i < 2; i++)
#pragma unroll
    for (int j = 0; j < NJ; j++) {
      int gn = n0 + wn + j * 16 + r;
      float bv = (EPI == 1) ? bias[zBias * z + gn] : 0.f;
#pragma unroll
      for (int t2 = 0; t2 < 4; t2++) {
        int gm = bm + wm + i * 16 + q * 4 + t2;
        if (gm < M) {
          float v = acc[i][j][t2];
          if (EPI == 1) { v += bv; v = v > 0.f ? v : expm1f(v); }
          C[(size_t)z * zC + (size_t)gm * ldc + gn] = v;
        }
      }
    }
}

// ---------- split-K reduce + mean-over-heads + bias ----------
__global__ __launch_bounds__(256)
void gat_reduce4(const float* __restrict__ p, const float* __restrict__ bias,
                 float* __restrict__ out, int MN) {
  int t = blockIdx.x * 256 + threadIdx.x;
  if (t >= MN) return;
  size_t mn = (size_t)MN;
  float v = p[t] + p[t + mn] + p[t + 2 * mn] + p[t + 3 * mn];
  out[t] = v * 0.125f + bias[t & 255];
}

extern "C" void kernel_launch(void* const* d_in, const int* in_sizes, int n_in,
                              void* d_out, int out_size, void* d_ws, size_t ws_size,
                              hipStream_t stream) {
  const float* x    = (const float*)d_in[0];
  const int* src1   = (const int*)d_in[1];
  const int* dst1   = (const int*)d_in[2];
  const int* src2   = (const int*)d_in[3];
  const int* dst2   = (const int*)d_in[4];
  const float* W1   = (const float*)d_in[5];
  const float* atts1 = (const float*)d_in[6];
  const float* attd1 = (const float*)d_in[7];
  const float* b1   = (const float*)d_in[8];
  const float* W2   = (const float*)d_in[9];
  const float* atts2 = (const float*)d_in[10];
  const float* attd2 = (const float*)d_in[11];
  const float* b2   = (const float*)d_in[12];
  const int E1 = in_sizes[1], E2 = in_sizes[3];

  uint8_t* p = (uint8_t*)d_ws;
  auto alloc = [&](size_t b) { uint8_t* r = p; p += (b + 255) & ~(size_t)255; return r; };
  auto al = [](size_t b) { return (b + 255) & ~(size_t)255; };
  // persistent (~52 MB)
  float* x1   = (float*)alloc((size_t)cN1 * cHC1 * 4);
  u16*   W1t  = (u16*)alloc((size_t)512 * 256 * 2);
  u16*   W2te = (u16*)alloc((size_t)256 * 4096 * 2);
  float* wts1 = (float*)alloc(8 * 256 * 4);
  float* wtd1 = (float*)alloc(8 * 256 * 4);
  float* wts2 = (float*)alloc(8 * 512 * 4);
  float* wtd2 = (float*)alloc(8 * 512 * 4);
  uint8_t* scratch = p;
  size_t usedPersist = (size_t)(scratch - (uint8_t*)d_ws);

  // phase A sizing: full M1=24000 if workspace allows (ws ~480MB -> yes), else 5x4800
  auto phaseA = [&](size_t m1) {
    return al(m1 * 2048 * 2) + al((size_t)cN0 * 32) + al((size_t)cN1 * 32) +
           al((size_t)E1 * 32) + al((size_t)E1 * 4) + al((size_t)(cN1 + 1) * 4) +
           al(256) + 2 * al((size_t)cN1 * 4);
  };
  int M1 = (usedPersist + phaseA(cN1) <= ws_size) ? cN1 : CH1;
  int nch1 = cN1 / M1;
  u16*   aggA  = (u16*)alloc((size_t)M1 * 2048 * 2);
  float* a_s1  = (float*)alloc((size_t)cN0 * 32);
  float* a_d1  = (float*)alloc((size_t)cN1 * 32);
  float* exs1  = (float*)alloc((size_t)E1 * 32);
  int*   srcs1 = (int*)alloc((size_t)E1 * 4);
  int*   off1  = (int*)alloc((size_t)(cN1 + 1) * 4);
  int*   bsum1 = (int*)alloc(256);
  uint8_t* zA = p;
  int*   cnt1 = (int*)alloc((size_t)cN1 * 4);
  int*   cur1 = (int*)alloc((size_t)cN1 * 4);
  size_t zAbytes = (size_t)(p - zA);

  // phase B sizing (aliases phase A): full M2=6000 if fits, else 2x3000
  auto phaseB = [&](size_t m2) {
    return al(m2 * 4096 * 2) + al(4ull * m2 * 256 * 4) + al((size_t)cN1 * 32) +
           al((size_t)cN2 * 32) + al((size_t)E2 * 32) + al((size_t)E2 * 4) +
           al((size_t)(cN2 + 1) * 4) + al(256) + 2 * al((size_t)cN2 * 4);
  };
  int M2 = (usedPersist + phaseB(6000) <= ws_size) ? 6000 : 3000;
  int nch2 = 6000 / M2;
  p = scratch;
  u16*   aggB  = (u16*)alloc((size_t)M2 * 4096 * 2);
  float* pbuf  = (float*)alloc(4ull * M2 * 256 * 4);
  float* a_s2  = (float*)alloc((size_t)cN1 * 32);
  float* a_d2  = (float*)alloc((size_t)cN2 * 32);
  float* exs2  = (float*)alloc((size_t)E2 * 32);
  int*   srcs2 = (int*)alloc((size_t)E2 * 4);
  int*   off2  = (int*)alloc((size_t)(cN2 + 1) * 4);
  int*   bsum2 = (int*)alloc(256);
  uint8_t* zB = p;
  int*   cnt2 = (int*)alloc((size_t)cN2 * 4);
  int*   cur2 = (int*)alloc((size_t)cN2 * 4);
  size_t zBbytes = (size_t)(p - zB);

  // ---- prep ----
  gat_w1t<<<(512 * 256 + 255) / 256, 256, 0, stream>>>(W1, W1t);
  gat_make_w2te<<<dim3(16, 8, 8), 256, 0, stream>>>(W2, W2te);
  gat_make_watt<<<2 * 256, 256, 0, stream>>>(W1, atts1, attd1, wts1, wtd1, 256, 64, 512);
  gat_make_watt<<<2 * 512, 256, 0, stream>>>(W2, atts2, attd2, wts2, wtd2, 512, 256, 2048);

  // ---- layer 1 ----
  hipMemsetAsync(zA, 0, zAbytes, stream);
  gat_scores_reg<<<1024, 256, 0, stream>>>(x, wts1, wtd1, a_s1, a_d1, cN0, cN1);
  gat_hist<<<(E1 + 255) / 256, 256, 0, stream>>>(dst1, cnt1, E1);
  {
    int nb = (cN1 + 1023) / 1024;  // 24
    gat_scan1<<<nb, 1024, 0, stream>>>(cnt1, off1, bsum1, cN1);
    gat_scan2<<<1, 64, 0, stream>>>(bsum1, nb, off1, cN1);
    gat_scan3<<<(cN1 + 255) / 256, 256, 0, stream>>>(off1, bsum1, cN1);
  }
  gat_scatter_edge<<<(E1 + 255) / 256, 256, 0, stream>>>(src1, dst1, a_s1, a_d1, off1, cur1, srcs1, exs1, E1);
  for (int c = 0; c < nch1; c++) {
    int d0 = c * M1;
    gat_gather_in1<<<M1, 256, 0, stream>>>(x, exs1, off1, srcs1, aggA, d0);
    gat_gemm<64, 1><<<dim3(M1 / 64, 1, 8), 256, 0, stream>>>(
        aggA, 2048, W1t, 256, x1 + (size_t)d0 * cHC1, cHC1,
        M1, 256, b1, /*zA*/256, /*zB*/64 * 256, /*zC*/64, /*zBias*/64);
  }

  // ---- layer 2 ----
  hipMemsetAsync(zB, 0, zBbytes, stream);
  gat_scores_w512<<<512, 256, 0, stream>>>(x1, wts2, wtd2, a_s2, a_d2, cN1, cN2);
  gat_hist<<<(E2 + 255) / 256, 256, 0, stream>>>(dst2, cnt2, E2);
  {
    int nb = (cN2 + 1023) / 1024;  // 6
    gat_scan1<<<nb, 1024, 0, stream>>>(cnt2, off2, bsum2, cN2);
    gat_scan2<<<1, 64, 0, stream>>>(bsum2, nb, off2, cN2);
    gat_scan3<<<(cN2 + 255) / 256, 256, 0, stream>>>(off2, bsum2, cN2);
  }
  gat_scatter_edge<<<(E2 + 255) / 256, 256, 0, stream>>>(src2, dst2, a_s2, a_d2, off2, cur2, srcs2, exs2, E2);
  for (int c = 0; c < nch2; c++) {
    int d0 = c * M2;
    gat_gather_in2<<<M2, 256, 0, stream>>>(x1, exs2, off2, srcs2, aggB, d0);
    gat_gemm<128, 0><<<dim3((M2 + 63) / 64, 2, 4), 256, 0, stream>>>(
        aggB, 4096, W2te, 4096, pbuf, 256,
        M2, 1024, nullptr, /*zA*/1024, /*zB*/1024, /*zC*/(long)M2 * 256, /*zBias*/0);
    gat_reduce4<<<(M2 * 256 + 255) / 256, 256, 0, stream>>>(
        pbuf, b2, (float*)d_out + (size_t)d0 * 256, M2 * 256);
  }
}

// Round 2
// 483.871 us; speedup vs baseline: 1.2411x; 1.0239x over previous
//
#include <hip/hip_runtime.h>
#include <hip/hip_bf16.h>
#include <cstdint>

typedef __attribute__((ext_vector_type(8))) short short8;
typedef __attribute__((ext_vector_type(4))) float floatx4;
typedef __hip_bfloat16 bf16;
typedef unsigned short u16;

static constexpr int cN0 = 120000, cN1 = 24000, cN2 = 6000;
static constexpr int cD = 256, cHC1 = 512;
static constexpr int CH1 = 4800;   // layer-1 fallback chunk (5 chunks, %64==0)

__device__ __forceinline__ float dot4(float4 a, float4 b) {
  return a.x * b.x + a.y * b.y + a.z * b.z + a.w * b.w;
}

// ---------- fused prep: W1t, W2te, watt1, watt2 in one launch ----------
// blocks [0,512): W1t[n*256+k] = bf16(W1[k*512+n])
// blocks [512,1536): W2te[c*4096+h*512+k] = bf16(W2[k*2048+h*256+c])
// blocks [1536,2048): watt layer1 (K=256,Ch=64,ldw=512)
// blocks [2048,3072): watt layer2 (K=512,Ch=256,ldw=2048)
__global__ __launch_bounds__(256)
void gat_prep(const float* __restrict__ W1, const float* __restrict__ W2,
              const float* __restrict__ as1, const float* __restrict__ ad1,
              const float* __restrict__ as2, const float* __restrict__ ad2,
              u16* __restrict__ W1t, u16* __restrict__ W2te,
              float* __restrict__ wts1, float* __restrict__ wtd1,
              float* __restrict__ wts2, float* __restrict__ wtd2) {
  __shared__ u16 tile[32][33];
  int b = (int)blockIdx.x;
  if (b < 512) {
    int t = b * 256 + threadIdx.x;  // t = n*256+k
    int n = t >> 8, k = t & 255;
    bf16 v = bf16(W1[(size_t)k * 512 + n]);
    W1t[t] = *(u16*)&v;
    return;
  }
  b -= 512;
  if (b < 1024) {
    int bx = b & 15, by = (b >> 4) & 7, h = b >> 7;
    int kt = bx * 32, ct = by * 32;
    int tx = threadIdx.x & 31, ty4 = (threadIdx.x >> 5) * 4;
#pragma unroll
    for (int i = 0; i < 4; i++) {
      int k = kt + ty4 + i, c = ct + tx;
      bf16 v = bf16(W2[(size_t)k * 2048 + h * 256 + c]);
      tile[ty4 + i][tx] = *(u16*)&v;
    }
    __syncthreads();
#pragma unroll
    for (int i = 0; i < 4; i++) {
      int c = ct + ty4 + i, k = kt + tx;
      W2te[(size_t)c * 4096 + h * 512 + k] = tile[tx][ty4 + i];
    }
    return;
  }
  b -= 1024;
  int lane = threadIdx.x & 63;
  int K, Ch, ldw, task;
  const float *W, *as, *ad;
  float *ws, *wd;
  if (b < 512) {
    K = 256; Ch = 64; ldw = 512; W = W1; as = as1; ad = ad1; ws = wts1; wd = wtd1;
    task = b * 4 + (threadIdx.x >> 6);
  } else {
    b -= 512;
    K = 512; Ch = 256; ldw = 2048; W = W2; as = as2; ad = ad2; ws = wts2; wd = wtd2;
    task = b * 4 + (threadIdx.x >> 6);
  }
  if (task >= 8 * K) return;
  int h = task / K, k = task - h * K;
  const float* Wr = W + (size_t)k * ldw + h * Ch;
  const float* asp = as + h * Ch;
  const float* adp = ad + h * Ch;
  float ss = 0.f, dd = 0.f;
  for (int c = lane; c < Ch; c += 64) {
    float wv = Wr[c];
    ss += wv * asp[c];
    dd += wv * adp[c];
  }
#pragma unroll
  for (int o = 32; o; o >>= 1) { ss += __shfl_down(ss, o); dd += __shfl_down(dd, o); }
  if (lane == 0) { ws[task] = ss; wd[task] = dd; }
}

// ---- transposed butterfly reduce: 16 partials over 64 lanes in 15 shfl ----
#define RSTAGE(HALF, MASK)                                              \
  {                                                                     \
    _Pragma("unroll") for (int j = 0; j < HALF; j++) {                  \
      float send = (lane & MASK) ? v[j] : v[j + HALF];                  \
      float rcv = __shfl_xor(send, MASK);                               \
      v[j] = ((lane & MASK) ? v[j + HALF] : v[j]) + rcv;                \
    }                                                                   \
  }

// ---------- scores K=256: one row per wave, w in 64 VGPRs ----------
__global__ __launch_bounds__(256)
void gat_scores_reg(const float* __restrict__ x, const float* __restrict__ wsrc,
                    const float* __restrict__ wdst, float* __restrict__ a_s,
                    float* __restrict__ a_d, int M, int MD) {
  int lane = threadIdx.x & 63;
  int wv = (blockIdx.x * 256 + threadIdx.x) >> 6;
  int nw = (gridDim.x * 256) >> 6;
  float4 w[16];
#pragma unroll
  for (int j = 0; j < 8; j++) {
    w[j]     = *(const float4*)&wsrc[j * 256 + lane * 4];
    w[j + 8] = *(const float4*)&wdst[j * 256 + lane * 4];
  }
  for (int row = wv; row < M; row += nw) {
    float4 xv = *(const float4*)&x[(size_t)row * 256 + lane * 4];
    float v[16];
#pragma unroll
    for (int j = 0; j < 16; j++) v[j] = dot4(xv, w[j]);
    RSTAGE(8, 1) RSTAGE(4, 2) RSTAGE(2, 4) RSTAGE(1, 8)
    v[0] += __shfl_xor(v[0], 16);
    v[0] += __shfl_xor(v[0], 32);
    if (lane < 16) {
      int o = ((lane & 1) << 3) | ((lane & 2) << 1) | ((lane & 4) >> 1) | ((lane & 8) >> 3);
      if (o < 8) a_s[row * 8 + o] = v[0];
      else if (row < MD) a_d[row * 8 + (o - 8)] = v[0];
    }
  }
}

// ---------- scores K=512: w staged in LDS (32 KB), one row per wave ----------
__global__ __launch_bounds__(256)
void gat_scores_w512(const float* __restrict__ x, const float* __restrict__ wsrc,
                     const float* __restrict__ wdst, float* __restrict__ a_s,
                     float* __restrict__ a_d, int M, int MD) {
  __shared__ float wl[16 * 512];
  int tid = threadIdx.x;
#pragma unroll
  for (int base = 0; base < 8192; base += 1024) {
    int idx = base + tid * 4;
    int j = idx >> 9, c = idx & 511;
    *(float4*)&wl[idx] = (j < 8) ? *(const float4*)&wsrc[j * 512 + c]
                                 : *(const float4*)&wdst[(j - 8) * 512 + c];
  }
  __syncthreads();
  int lane = tid & 63;
  int wv = (blockIdx.x * 256 + tid) >> 6;
  int nw = (gridDim.x * 256) >> 6;
  for (int row = wv; row < M; row += nw) {
    float4 xa = *(const float4*)&x[(size_t)row * 512 + lane * 4];
    float4 xb = *(const float4*)&x[(size_t)row * 512 + 256 + lane * 4];
    float v[16];
#pragma unroll
    for (int j = 0; j < 16; j++) {
      float4 wa = *(const float4*)&wl[j * 512 + lane * 4];
      float4 wb = *(const float4*)&wl[j * 512 + 256 + lane * 4];
      v[j] = dot4(xa, wa) + dot4(xb, wb);
    }
    RSTAGE(8, 1) RSTAGE(4, 2) RSTAGE(2, 4) RSTAGE(1, 8)
    v[0] += __shfl_xor(v[0], 16);
    v[0] += __shfl_xor(v[0], 32);
    if (lane < 16) {
      int o = ((lane & 1) << 3) | ((lane & 2) << 1) | ((lane & 4) >> 1) | ((lane & 8) >> 3);
      if (o < 8) a_s[row * 8 + o] = v[0];
      else if (row < MD) a_d[row * 8 + (o - 8)] = v[0];
    }
  }
}

// ---------- CSR build ----------
__global__ __launch_bounds__(256)
void gat_hist(const int* __restrict__ dstv, int* __restrict__ cnt, int E) {
  int t = blockIdx.x * 256 + threadIdx.x;
  if (t < E) atomicAdd(&cnt[dstv[t]], 1);
}

// 2-kernel parallel exclusive scan
__global__ __launch_bounds__(1024)
void gat_scan1(const int* __restrict__ cnt, int* __restrict__ off,
               int* __restrict__ bsum, int n) {
  __shared__ int wsum[16];
  int t = threadIdx.x, lane = t & 63, wid = t >> 6;
  int idx = blockIdx.x * 1024 + t;
  int v = (idx < n) ? cnt[idx] : 0;
  int x = v;
#pragma unroll
  for (int d = 1; d < 64; d <<= 1) { int y = __shfl_up(x, d); if (lane >= d) x += y; }
  if (lane == 63) wsum[wid] = x;
  __syncthreads();
  if (t < 16) {
    int s = wsum[t];
#pragma unroll
    for (int d = 1; d < 16; d <<= 1) { int y = __shfl_up(s, d); if (t >= d) s += y; }
    wsum[t] = s;
  }
  __syncthreads();
  int excl = (wid ? wsum[wid - 1] : 0) + x - v;
  if (idx < n) off[idx] = excl;
  if (t == 1023) bsum[blockIdx.x] = wsum[15];
}

// adds per-block offsets (nb <= 24: each block serially prefixes bsum)
__global__ __launch_bounds__(256)
void gat_scan3(int* __restrict__ off, const int* __restrict__ bsum, int n, int nb) {
  int i = blockIdx.x * 256 + threadIdx.x;
  int blk = (blockIdx.x * 256) >> 10;  // uniform across the block
  int add = 0;
  for (int b = 0; b < blk; b++) add += bsum[b];
  if (i < n) off[i] += add;
  if (i == 0) {
    int tot = 0;
    for (int b = 0; b < nb; b++) tot += bsum[b];
    off[n] = tot;
  }
}

// ---------- fused scatter+edge ----------
__global__ __launch_bounds__(256)
void gat_scatter_edge(const int* __restrict__ src, const int* __restrict__ dstv,
                      const float* __restrict__ a_s, const float* __restrict__ a_d,
                      const int* __restrict__ off, int* __restrict__ cur,
                      int* __restrict__ srcs, float* __restrict__ exs, int E) {
  int t = blockIdx.x * 256 + threadIdx.x;
  if (t >= E) return;
  int s = src[t], d = dstv[t];
  int slot = off[d] + atomicAdd(&cur[d], 1);
  srcs[slot] = s;
  const float* as = a_s + (size_t)s * 8;
  const float* ad = a_d + (size_t)d * 8;
  float4 s0 = *(const float4*)as, s1 = *(const float4*)(as + 4);
  float4 d0 = *(const float4*)ad, d1 = *(const float4*)(ad + 4);
  float ev[8] = { s0.x + d0.x, s0.y + d0.y, s0.z + d0.z, s0.w + d0.w,
                  s1.x + d1.x, s1.y + d1.y, s1.z + d1.z, s1.w + d1.w };
  float exv[8];
#pragma unroll
  for (int h = 0; h < 8; h++) {
    float e = ev[h];
    e = e > 0.f ? e : 0.2f * e;
    exv[h] = expf(e);  // shift-invariant softmax; |e| <~ 8 so no overflow
  }
  float4* op = (float4*)(exs + (size_t)slot * 8);
  op[0] = make_float4(exv[0], exv[1], exv[2], exv[3]);
  op[1] = make_float4(exv[4], exv[5], exv[6], exv[7]);
}

// ---------- per-dst denominators (no atomics) ----------
__global__ __launch_bounds__(256)
void gat_denom(const float* __restrict__ exs, const int* __restrict__ off,
               float* __restrict__ den, int N) {
  int lane = threadIdx.x & 63;
  int d = blockIdx.x * 4 + (threadIdx.x >> 6);
  if (d >= N) return;
  int beg = off[d], end = off[d + 1];
  float s = 0.f;
  for (size_t idx = (size_t)beg * 8 + lane; idx < (size_t)end * 8; idx += 64)
    s += exs[idx];
#pragma unroll
  for (int o = 32; o >= 8; o >>= 1) s += __shfl_down(s, o);
  if (lane < 8) den[(size_t)d * 8 + lane] = s;
}

// ---------- unified gather: 1 col/thread, 4-edge unroll, pure-fmac inner ----------
// CDIM = row width of x (256 for layer1, 512 for layer2); blockDim == CDIM
template<int CDIM>
__global__ __launch_bounds__(CDIM)
void gat_gather(const float* __restrict__ x, const float* __restrict__ exs,
                const float* __restrict__ den, const int* __restrict__ off,
                const int* __restrict__ srcs, u16* __restrict__ agg, int d0) {
  int d = d0 + blockIdx.x, t = threadIdx.x;  // t in [0, CDIM)
  int beg = off[d], end = off[d + 1];
  float inv[8];
#pragma unroll
  for (int j = 0; j < 8; j++) {
    float dv = den[(size_t)d * 8 + j];
    inv[j] = dv > 0.f ? 1.f / dv : 0.f;  // zero-degree -> 0 (matches ref)
  }
  float acc[8] = {};
  const float* xb = x + t;
  int i = beg;
  for (; i + 4 <= end; i += 4) {
    int s0 = srcs[i], s1 = srcs[i + 1], s2 = srcs[i + 2], s3 = srcs[i + 3];
    float xv0 = xb[(size_t)s0 * CDIM];
    float xv1 = xb[(size_t)s1 * CDIM];
    float xv2 = xb[(size_t)s2 * CDIM];
    float xv3 = xb[(size_t)s3 * CDIM];
    float4 e0a = *(const float4*)&exs[(size_t)i * 8];
    float4 e0b = *(const float4*)&exs[(size_t)i * 8 + 4];
    float4 e1a = *(const float4*)&exs[(size_t)(i + 1) * 8];
    float4 e1b = *(const float4*)&exs[(size_t)(i + 1) * 8 + 4];
    float4 e2a = *(const float4*)&exs[(size_t)(i + 2) * 8];
    float4 e2b = *(const float4*)&exs[(size_t)(i + 2) * 8 + 4];
    float4 e3a = *(const float4*)&exs[(size_t)(i + 3) * 8];
    float4 e3b = *(const float4*)&exs[(size_t)(i + 3) * 8 + 4];
    acc[0] += e0a.x * xv0 + e1a.x * xv1 + e2a.x * xv2 + e3a.x * xv3;
    acc[1] += e0a.y * xv0 + e1a.y * xv1 + e2a.y * xv2 + e3a.y * xv3;
    acc[2] += e0a.z * xv0 + e1a.z * xv1 + e2a.z * xv2 + e3a.z * xv3;
    acc[3] += e0a.w * xv0 + e1a.w * xv1 + e2a.w * xv2 + e3a.w * xv3;
    acc[4] += e0b.x * xv0 + e1b.x * xv1 + e2b.x * xv2 + e3b.x * xv3;
    acc[5] += e0b.y * xv0 + e1b.y * xv1 + e2b.y * xv2 + e3b.y * xv3;
    acc[6] += e0b.z * xv0 + e1b.z * xv1 + e2b.z * xv2 + e3b.z * xv3;
    acc[7] += e0b.w * xv0 + e1b.w * xv1 + e2b.w * xv2 + e3b.w * xv3;
  }
  for (; i < end; i++) {
    int s = srcs[i];
    float xv = xb[(size_t)s * CDIM];
    float4 ea = *(const float4*)&exs[(size_t)i * 8];
    float4 eb = *(const float4*)&exs[(size_t)i * 8 + 4];
    acc[0] += ea.x * xv; acc[1] += ea.y * xv; acc[2] += ea.z * xv; acc[3] += ea.w * xv;
    acc[4] += eb.x * xv; acc[5] += eb.y * xv; acc[6] += eb.z * xv; acc[7] += eb.w * xv;
  }
  u16* ap = agg + (size_t)blockIdx.x * (8 * CDIM) + t;
#pragma unroll
  for (int j = 0; j < 8; j++) {
    bf16 v = bf16(acc[j] * inv[j]);
    ap[(size_t)j * CDIM] = *(u16*)&v;
  }
}

// ---------- GEMM: C = A[M,K] @ Bt[N,K]^T (bf16 in, f32 out), M-guarded ----------
// XOR-swizzled LDS: conflict-free b128. EPI=0: raw partial; EPI=1: elu(v+bias)
template<int BN, int EPI>
__global__ __launch_bounds__(256)
void gat_gemm(const u16* __restrict__ A, long lda, const u16* __restrict__ Bt, long ldb,
              float* __restrict__ C, long ldc, int M, int K,
              const float* __restrict__ bias, int zA, int zB, long zC, int zBias) {
  __shared__ __align__(16) u16 Al[64 * 64];
  __shared__ __align__(16) u16 Bl[BN * 64];
  const int tid = threadIdx.x;
  const int bm = blockIdx.x << 6;
  const int n0 = blockIdx.y * BN;
  const int z = blockIdx.z;
  const u16* Ab = A + (size_t)z * zA;
  const u16* Bb = Bt + (size_t)z * zB + (size_t)n0 * ldb;
  const int wid = tid >> 6, lane = tid & 63;
  const int wm = (wid & 1) << 5, wn = (wid >> 1) * (BN / 2);
  const int q = lane >> 4, r = lane & 15;
  constexpr int NJ = BN / 32;
  floatx4 acc[2][NJ] = {};
  const int arow = tid >> 3;      // 0..31
  const int chunk = tid & 7;      // 8-u16 chunk index
  const int acol = chunk << 3;
  for (int k0 = 0; k0 < K; k0 += 64) {
    __syncthreads();
#pragma unroll
    for (int rr = 0; rr < 2; rr++) {
      int row = arow + rr * 32;
      int gr = bm + row; if (gr >= M) gr = M - 1;
      *(uint4*)&Al[row * 64 + ((chunk ^ (row & 7)) << 3)] =
          *(const uint4*)&Ab[(size_t)gr * lda + k0 + acol];
    }
#pragma unroll
    for (int rr = 0; rr < BN / 32; rr++) {
      int row = arow + rr * 32;
      *(uint4*)&Bl[row * 64 + ((chunk ^ (row & 7)) << 3)] =
          *(const uint4*)&Bb[(size_t)row * ldb + k0 + acol];
    }
    __syncthreads();
#pragma unroll
    for (int kk = 0; kk < 64; kk += 32) {
      const int cs = (((kk >> 3) + q) ^ (r & 7)) << 3;
      short8 af[2], bfr[NJ];
#pragma unroll
      for (int i = 0; i < 2; i++)  af[i]  = *(const short8*)&Al[(wm + i * 16 + r) * 64 + cs];
#pragma unroll
      for (int j = 0; j < NJ; j++) bfr[j] = *(const short8*)&Bl[(wn + j * 16 + r) * 64 + cs];
#pragma unroll
      for (int i = 0; i < 2; i++)
#pragma unroll
        for (int j = 0; j < NJ; j++)
          acc[i][j] = __builtin_amdgcn_mfma_f32_16x16x32_bf16(af[i], bfr[j], acc[i][j], 0, 0, 0);
    }
  }
  // C/D layout: col = lane&15 (n), row = quad*4 + reg (m)
#pragma unroll
  for (int i = 0; i < 2; i++)
#pragma unroll
    for (int j = 0; j < NJ; j++) {
      int gn = n0 + wn + j * 16 + r;
      float bv = (EPI == 1) ? bias[zBias * z + gn] : 0.f;
#pragma unroll
      for (int t2 = 0; t2 < 4; t2++) {
        int gm = bm + wm + i * 16 + q * 4 + t2;
        if (gm < M) {
          float v = acc[i][j][t2];
          if (EPI == 1) { v += bv; v = v > 0.f ? v : expm1f(v); }
          C[(size_t)z * zC + (size_t)gm * ldc + gn] = v;
        }
      }
    }
}

// ---------- split-K reduce + mean-over-heads + bias ----------
__global__ __launch_bounds__(256)
void gat_reduce4(const float* __restrict__ p, const float* __restrict__ bias,
                 float* __restrict__ out, int MN) {
  int t = blockIdx.x * 256 + threadIdx.x;
  if (t >= MN) return;
  size_t mn = (size_t)MN;
  float v = p[t] + p[t + mn] + p[t + 2 * mn] + p[t + 3 * mn];
  out[t] = v * 0.125f + bias[t & 255];
}

extern "C" void kernel_launch(void* const* d_in, const int* in_sizes, int n_in,
                              void* d_out, int out_size, void* d_ws, size_t ws_size,
                              hipStream_t stream) {
  const float* x    = (const float*)d_in[0];
  const int* src1   = (const int*)d_in[1];
  const int* dst1   = (const int*)d_in[2];
  const int* src2   = (const int*)d_in[3];
  const int* dst2   = (const int*)d_in[4];
  const float* W1   = (const float*)d_in[5];
  const float* atts1 = (const float*)d_in[6];
  const float* attd1 = (const float*)d_in[7];
  const float* b1   = (const float*)d_in[8];
  const float* W2   = (const float*)d_in[9];
  const float* atts2 = (const float*)d_in[10];
  const float* attd2 = (const float*)d_in[11];
  const float* b2   = (const float*)d_in[12];
  const int E1 = in_sizes[1], E2 = in_sizes[3];

  uint8_t* p = (uint8_t*)d_ws;
  auto alloc = [&](size_t b) { uint8_t* r = p; p += (b + 255) & ~(size_t)255; return r; };
  auto al = [](size_t b) { return (b + 255) & ~(size_t)255; };
  // persistent (~52 MB)
  float* x1   = (float*)alloc((size_t)cN1 * cHC1 * 4);
  u16*   W1t  = (u16*)alloc((size_t)512 * 256 * 2);
  u16*   W2te = (u16*)alloc((size_t)256 * 4096 * 2);
  float* wts1 = (float*)alloc(8 * 256 * 4);
  float* wtd1 = (float*)alloc(8 * 256 * 4);
  float* wts2 = (float*)alloc(8 * 512 * 4);
  float* wtd2 = (float*)alloc(8 * 512 * 4);
  uint8_t* scratch = p;
  size_t usedPersist = (size_t)(scratch - (uint8_t*)d_ws);

  // phase A sizing: full M1=24000 if workspace allows (ws ~480MB -> yes), else 5x4800
  auto phaseA = [&](size_t m1) {
    return al(m1 * 2048 * 2) + al((size_t)cN0 * 32) + al((size_t)cN1 * 32) +
           al((size_t)E1 * 32) + al((size_t)E1 * 4) + al((size_t)(cN1 + 1) * 4) +
           al(256) + al((size_t)cN1 * 32) + 2 * al((size_t)cN1 * 4);
  };
  int M1 = (usedPersist + phaseA(cN1) <= ws_size) ? cN1 : CH1;
  int nch1 = cN1 / M1;
  u16*   aggA  = (u16*)alloc((size_t)M1 * 2048 * 2);
  float* a_s1  = (float*)alloc((size_t)cN0 * 32);
  float* a_d1  = (float*)alloc((size_t)cN1 * 32);
  float* exs1  = (float*)alloc((size_t)E1 * 32);
  int*   srcs1 = (int*)alloc((size_t)E1 * 4);
  int*   off1  = (int*)alloc((size_t)(cN1 + 1) * 4);
  int*   bsum1 = (int*)alloc(256);
  float* den1  = (float*)alloc((size_t)cN1 * 32);
  uint8_t* zA = p;
  int*   cnt1 = (int*)alloc((size_t)cN1 * 4);
  int*   cur1 = (int*)alloc((size_t)cN1 * 4);
  size_t zAbytes = (size_t)(p - zA);

  // phase B sizing (aliases phase A): full M2=6000 if fits, else 2x3000
  auto phaseB = [&](size_t m2) {
    return al(m2 * 4096 * 2) + al(4ull * m2 * 256 * 4) + al((size_t)cN1 * 32) +
           al((size_t)cN2 * 32) + al((size_t)E2 * 32) + al((size_t)E2 * 4) +
           al((size_t)(cN2 + 1) * 4) + al(256) + al((size_t)cN2 * 32) +
           2 * al((size_t)cN2 * 4);
  };
  int M2 = (usedPersist + phaseB(6000) <= ws_size) ? 6000 : 3000;
  int nch2 = 6000 / M2;
  p = scratch;
  u16*   aggB  = (u16*)alloc((size_t)M2 * 4096 * 2);
  float* pbuf  = (float*)alloc(4ull * M2 * 256 * 4);
  float* a_s2  = (float*)alloc((size_t)cN1 * 32);
  float* a_d2  = (float*)alloc((size_t)cN2 * 32);
  float* exs2  = (float*)alloc((size_t)E2 * 32);
  int*   srcs2 = (int*)alloc((size_t)E2 * 4);
  int*   off2  = (int*)alloc((size_t)(cN2 + 1) * 4);
  int*   bsum2 = (int*)alloc(256);
  float* den2  = (float*)alloc((size_t)cN2 * 32);
  uint8_t* zB = p;
  int*   cnt2 = (int*)alloc((size_t)cN2 * 4);
  int*   cur2 = (int*)alloc((size_t)cN2 * 4);
  size_t zBbytes = (size_t)(p - zB);

  // ---- prep (fused) ----
  gat_prep<<<3072, 256, 0, stream>>>(W1, W2, atts1, attd1, atts2, attd2,
                                     W1t, W2te, wts1, wtd1, wts2, wtd2);

  // ---- layer 1 ----
  hipMemsetAsync(zA, 0, zAbytes, stream);
  gat_scores_reg<<<1024, 256, 0, stream>>>(x, wts1, wtd1, a_s1, a_d1, cN0, cN1);
  gat_hist<<<(E1 + 255) / 256, 256, 0, stream>>>(dst1, cnt1, E1);
  {
    int nb = (cN1 + 1023) / 1024;  // 24
    gat_scan1<<<nb, 1024, 0, stream>>>(cnt1, off1, bsum1, cN1);
    gat_scan3<<<(cN1 + 255) / 256, 256, 0, stream>>>(off1, bsum1, cN1, nb);
  }
  gat_scatter_edge<<<(E1 + 255) / 256, 256, 0, stream>>>(src1, dst1, a_s1, a_d1, off1, cur1, srcs1, exs1, E1);
  gat_denom<<<(cN1 + 3) / 4, 256, 0, stream>>>(exs1, off1, den1, cN1);
  for (int c = 0; c < nch1; c++) {
    int d0 = c * M1;
    gat_gather<256><<<M1, 256, 0, stream>>>(x, exs1, den1, off1, srcs1, aggA, d0);
    gat_gemm<64, 1><<<dim3(M1 / 64, 1, 8), 256, 0, stream>>>(
        aggA, 2048, W1t, 256, x1 + (size_t)d0 * cHC1, cHC1,
        M1, 256, b1, /*zA*/256, /*zB*/64 * 256, /*zC*/64, /*zBias*/64);
  }

  // ---- layer 2 ----
  hipMemsetAsync(zB, 0, zBbytes, stream);
  gat_scores_w512<<<512, 256, 0, stream>>>(x1, wts2, wtd2, a_s2, a_d2, cN1, cN2);
  gat_hist<<<(E2 + 255) / 256, 256, 0, stream>>>(dst2, cnt2, E2);
  {
    int nb = (cN2 + 1023) / 1024;  // 6
    gat_scan1<<<nb, 1024, 0, stream>>>(cnt2, off2, bsum2, cN2);
    gat_scan3<<<(cN2 + 255) / 256, 256, 0, stream>>>(off2, bsum2, cN2, nb);
  }
  gat_scatter_edge<<<(E2 + 255) / 256, 256, 0, stream>>>(src2, dst2, a_s2, a_d2, off2, cur2, srcs2, exs2, E2);
  gat_denom<<<(cN2 + 3) / 4, 256, 0, stream>>>(exs2, off2, den2, cN2);
  for (int c = 0; c < nch2; c++) {
    int d0 = c * M2;
    gat_gather<512><<<M2, 512, 0, stream>>>(x1, exs2, den2, off2, srcs2, aggB, d0);
    gat_gemm<128, 0><<<dim3((M2 + 63) / 64, 2, 4), 256, 0, stream>>>(
        aggB, 4096, W2te, 4096, pbuf, 256,
        M2, 1024, nullptr, /*zA*/1024, /*zB*/1024, /*zC*/(long)M2 * 256, /*zBias*/0);
    gat_reduce4<<<(M2 * 256 + 255) / 256, 256, 0, stream>>>(
        pbuf, b2, (float*)d_out + (size_t)d0 * 256, M2 * 256);
  }
}